// Round 11
// baseline (67.966 us; speedup 1.0000x reference)
//
#include <hip/hip_runtime.h>
#include <hip/hip_bf16.h>
#include <math.h>

typedef __attribute__((ext_vector_type(4))) float f32x4;
typedef __attribute__((ext_vector_type(8))) short bf16x8;

#define NB    64
#define LQ    32
#define LDOC  256
#define HDIM  768
#define DDIM  128
#define NTOK_Q (NB * LQ)        // 2048
#define NTOK_D (NB * LDOC)      // 16384
#define NTOK   (NTOK_Q + NTOK_D) // 18432

// ws layout (bytes):
#define WS_OFF_W    0           // Wbf   : 128*768 bf16   (196608)
#define WS_OFF_MASK 196608      // maskT : 64*16 ushort (2KB)
#define WS_OFF_QN   212992      // Qn    : 2048*128 bf16
#define WS_OFF_DN   737280      // Dn    : 16384*128 bf16

__device__ inline short f2bf(float f) {
    unsigned u = __float_as_uint(f);
    u = (u + 0x7fffu + ((u >> 16) & 1u)) >> 16;   // RNE
    return (short)u;
}

// ---------------------------------------------------------------------------
// prep: blocks 0..95 convert W fp32->bf16; block 96 builds bit-transposed mask.
__global__ void prep(const float* __restrict__ W, short* __restrict__ Wbf,
                     const unsigned char* __restrict__ mraw,
                     unsigned short* __restrict__ maskT) {
    if (blockIdx.x < 96) {
        int i = blockIdx.x * 256 + threadIdx.x;
        float4 v = *(const float4*)(W + (size_t)i * 4);
        short4 o;
        o.x = f2bf(v.x); o.y = f2bf(v.y); o.z = f2bf(v.z); o.w = f2bf(v.w);
        *(short4*)(Wbf + (size_t)i * 4) = o;
        return;
    }
    __shared__ int dword_ok_s;
    if (threadIdx.x == 0) dword_ok_s = 1;
    __syncthreads();
    const unsigned* dw = (const unsigned*)mraw;
    int ok = 1;
    for (int i = threadIdx.x; i < 4096; i += 256) {   // first 16KB: safe both ways
        unsigned v = dw[i];
        if (!(v == 0u || v == 1u || v == 0x3F800000u)) ok = 0;
    }
    if (!ok) atomicAnd(&dword_ok_s, 0);
    __syncthreads();
    const int isdw = dword_ok_s;
    for (int w = threadIdx.x; w < 1024; w += 256) {   // word w: c=w>>4, lane-col=w&15
        const int c = w >> 4, lcc = w & 15;
        unsigned bits = 0;
        if (isdw) {
            for (int nt = 0; nt < 16; ++nt)
                bits |= (dw[c * 256 + nt * 16 + lcc] ? 1u : 0u) << nt;
        } else {
            for (int nt = 0; nt < 16; ++nt)
                bits |= (mraw[c * 256 + nt * 16 + lcc] ? 1u : 0u) << nt;
        }
        maskT[w] = (unsigned short)bits;
    }
}

// ---------------------------------------------------------------------------
// Projection + L2 norm v11: LDS-FREE, BARRIER-FREE streaming MFMA.
// Block = 16-row panel, 4 waves: (col-half ch) x (K-half kh). Each wave:
// 12 ks-steps of K=32; A frags loaded per-lane straight from global fp32
// (frag row == lane&15), B frags from L2-resident Wbf; depth-2 register
// staging pinned with sched_barrier. No LDS/barrier until the epilogue
// (K-half combine + norms).
__global__ __launch_bounds__(256)
void proj_norm(const float* __restrict__ Qh, const float* __restrict__ Dh,
               const short* __restrict__ Wbf,
               short* __restrict__ Qn, short* __restrict__ Dn) {
    const int tid  = threadIdx.x;
    const int lane = tid & 63;
    const int wave = tid >> 6;           // 0..3
    const int ch   = wave & 1;           // 64-col half
    const int kh   = wave >> 1;          // 384-deep K half
    const int g    = lane >> 4;
    const int lc   = lane & 15;
    const int row0 = blockIdx.x * 16;

    const float* Asrc = (row0 < NTOK_Q) ? Qh + (size_t)row0 * HDIM
                                        : Dh + (size_t)(row0 - NTOK_Q) * HDIM;
    // lane's A address for ks: aptr + ks*32  (A frag row = lc, cols g*8..g*8+8)
    const float* aptr = Asrc + (size_t)lc * HDIM + kh * 384 + g * 8;
    // B frag bases for the 4 n-tiles of this col-half
    const short* b0 = Wbf + (size_t)(ch * 64 +  0 + lc) * HDIM + kh * 384 + g * 8;
    const short* b1 = Wbf + (size_t)(ch * 64 + 16 + lc) * HDIM + kh * 384 + g * 8;
    const short* b2 = Wbf + (size_t)(ch * 64 + 32 + lc) * HDIM + kh * 384 + g * 8;
    const short* b3 = Wbf + (size_t)(ch * 64 + 48 + lc) * HDIM + kh * 384 + g * 8;

    f32x4 acc[4];
#pragma unroll
    for (int nt = 0; nt < 4; ++nt) acc[nt] = (f32x4){0.f, 0.f, 0.f, 0.f};

    float4 sa[2][2];
    bf16x8 sb[2][4];
    sa[0][0] = *(const float4*)(aptr);
    sa[0][1] = *(const float4*)(aptr + 4);
    sb[0][0] = *(const bf16x8*)(b0);
    sb[0][1] = *(const bf16x8*)(b1);
    sb[0][2] = *(const bf16x8*)(b2);
    sb[0][3] = *(const bf16x8*)(b3);

#pragma unroll
    for (int ks = 0; ks < 12; ++ks) {
        const int cur = ks & 1, nxt = cur ^ 1;
        if (ks < 11) {                       // issue next step's loads first
            const int o = (ks + 1) * 32;
            sa[nxt][0] = *(const float4*)(aptr + o);
            sa[nxt][1] = *(const float4*)(aptr + o + 4);
            sb[nxt][0] = *(const bf16x8*)(b0 + o);
            sb[nxt][1] = *(const bf16x8*)(b1 + o);
            sb[nxt][2] = *(const bf16x8*)(b2 + o);
            sb[nxt][3] = *(const bf16x8*)(b3 + o);
        }
        __builtin_amdgcn_sched_barrier(0);   // pin load issue above this step's MFMAs
        bf16x8 af;
        af[0] = f2bf(sa[cur][0].x); af[1] = f2bf(sa[cur][0].y);
        af[2] = f2bf(sa[cur][0].z); af[3] = f2bf(sa[cur][0].w);
        af[4] = f2bf(sa[cur][1].x); af[5] = f2bf(sa[cur][1].y);
        af[6] = f2bf(sa[cur][1].z); af[7] = f2bf(sa[cur][1].w);
#pragma unroll
        for (int nt = 0; nt < 4; ++nt)
            acc[nt] = __builtin_amdgcn_mfma_f32_16x16x32_bf16(af, sb[cur][nt], acc[nt], 0, 0, 0);
    }

    // ---- epilogue: K-half combine (LDS), norms, store ----
    __shared__ float accx[2][64][16];    // [ch][lane][reg]  (8 KB)
    __shared__ float norms[2][16];

    if (kh == 1) {
#pragma unroll
        for (int nt = 0; nt < 4; ++nt)
            *(f32x4*)&accx[ch][lane][nt * 4] = acc[nt];
    }
    __syncthreads();

    if (kh == 0) {
#pragma unroll
        for (int nt = 0; nt < 4; ++nt)
            acc[nt] += *(const f32x4*)&accx[ch][lane][nt * 4];

        float part[4];
#pragma unroll
        for (int i = 0; i < 4; ++i) {
            float s = 0.f;
#pragma unroll
            for (int nt = 0; nt < 4; ++nt) s += acc[nt][i] * acc[nt][i];
            s += __shfl_xor(s, 1);
            s += __shfl_xor(s, 2);
            s += __shfl_xor(s, 4);
            s += __shfl_xor(s, 8);
            part[i] = s;
        }
        if (lc == 0) {
#pragma unroll
            for (int i = 0; i < 4; ++i) norms[ch][g * 4 + i] = part[i];
        }
    }
    __syncthreads();

    if (kh == 0) {
        short* Obase = (row0 < NTOK_Q) ? Qn + (size_t)row0 * DDIM
                                       : Dn + (size_t)(row0 - NTOK_Q) * DDIM;
#pragma unroll
        for (int i = 0; i < 4; ++i) {
            const int rloc = g * 4 + i;              // C row = (lane>>4)*4 + i
            const float tot = norms[0][rloc] + norms[1][rloc];
            const float inv = 1.f / fmaxf(sqrtf(tot), 1e-12f);
            short* dst = Obase + (size_t)rloc * DDIM + ch * 64;
#pragma unroll
            for (int nt = 0; nt < 4; ++nt)
                dst[nt * 16 + lc] = f2bf(acc[nt][i] * inv);
        }
    }
}

// ---------------------------------------------------------------------------
// MaxSim v5 (round-10, reg-staged): block = (c, 8 b's), 8 waves; wave <-> one
// b (32 q-rows x 256 n). D[c] in 4 chunks of 64 rows, double-buffered.
__global__ __launch_bounds__(512)
void maxsim(const short* __restrict__ Qn, const short* __restrict__ Dn,
            const unsigned short* __restrict__ maskT, float* __restrict__ out) {
    const int x  = blockIdx.x & 7;            // XCD (perf heuristic only)
    const int m8 = (blockIdx.x >> 3) & 7;
    const int bg = blockIdx.x >> 6;           // b-group (8 b's)
    const int c  = x * 8 + m8;                // all 8 bg's of a c on one XCD

    const int tid  = threadIdx.x;
    const int wave = tid >> 6;                // 0..7  <-> local b
    const int lane = tid & 63;
    const int g = lane >> 4, lc = lane & 15;

    __shared__ alignas(16) short Ds[2][8192];   // [buf][64 rows * 128], 16KB each

    const short* dsrc = Dn + (size_t)c * LDOC * DDIM;

    const int r0 = tid >> 4,          v0 = tid & 15;
    const int r1 = (512 + tid) >> 4,  v1 = v0;
    const int dd0 = r0 * DDIM + (v0 ^ (r0 & 15)) * 8;
    const int dd1 = r1 * DDIM + (v1 ^ (r1 & 15)) * 8;
    bf16x8 dr0, dr1;

    auto LOADS = [&](int chk) {
        dr0 = *(const bf16x8*)(dsrc + (size_t)(chk * 64 + r0) * DDIM + v0 * 8);
        dr1 = *(const bf16x8*)(dsrc + (size_t)(chk * 64 + r1) * DDIM + v1 * 8);
    };
    auto WRITES = [&](int buf) {
        *(bf16x8*)(&Ds[buf][dd0]) = dr0;
        *(bf16x8*)(&Ds[buf][dd1]) = dr1;
    };

    LOADS(0);
    WRITES(0);

    bf16x8 qf[2][4];
    const int qrow0 = bg * 256 + wave * 32;
#pragma unroll
    for (int m = 0; m < 2; ++m) {
        const short* qb = Qn + (size_t)(qrow0 + m * 16 + lc) * DDIM;
#pragma unroll
        for (int ks = 0; ks < 4; ++ks)
            qf[m][ks] = *(const bf16x8*)(qb + ks * 32 + g * 8);
    }
    const unsigned mbits = maskT[c * 16 + lc];    // bit nt = mask[c][nt*16+lc]

    __syncthreads();   // chunk 0 written

    float rmax[2][4];
#pragma unroll
    for (int m = 0; m < 2; ++m)
#pragma unroll
        for (int i = 0; i < 4; ++i) rmax[m][i] = -INFINITY;

    for (int chk = 0; chk < 4; ++chk) {
        const int buf = chk & 1;
        if (chk < 3) LOADS(chk + 1);              // fly under this chunk's compute
        __builtin_amdgcn_sched_barrier(0);
        const short* Db = &Ds[buf][0];
#pragma unroll
        for (int j = 0; j < 4; ++j) {
            const int rowl = j * 16 + lc;
            bf16x8 bf[4];
#pragma unroll
            for (int ks = 0; ks < 4; ++ks) {
                const int c16 = (ks * 4 + g) ^ lc;     // read-side swizzle
                bf[ks] = *(const bf16x8*)(Db + (size_t)rowl * DDIM + c16 * 8);
            }
            const bool on = (mbits >> (chk * 4 + j)) & 1;
#pragma unroll
            for (int m = 0; m < 2; ++m) {
                f32x4 acc = (f32x4){0.f, 0.f, 0.f, 0.f};
#pragma unroll
                for (int ks = 0; ks < 4; ++ks)
                    acc = __builtin_amdgcn_mfma_f32_16x16x32_bf16(qf[m][ks], bf[ks], acc, 0, 0, 0);
#pragma unroll
                for (int i = 0; i < 4; ++i)
                    rmax[m][i] = on ? fmaxf(rmax[m][i], acc[i]) : rmax[m][i];
            }
        }
        if (chk < 3) WRITES(buf ^ 1);
        __syncthreads();
    }

    float s = 0.f;
#pragma unroll
    for (int m = 0; m < 2; ++m)
#pragma unroll
        for (int i = 0; i < 4; ++i) {
            float r = rmax[m][i];
            r = fmaxf(r, __shfl_xor(r, 1));
            r = fmaxf(r, __shfl_xor(r, 2));
            r = fmaxf(r, __shfl_xor(r, 4));
            r = fmaxf(r, __shfl_xor(r, 8));
            s += r;
        }
    s += __shfl_xor(s, 16);
    s += __shfl_xor(s, 32);

    if (lane == 0) {
        const int b = bg * 8 + wave;
        out[(size_t)b * NB + c] = s;
    }
}

// ---------------------------------------------------------------------------
extern "C" void kernel_launch(void* const* d_in, const int* in_sizes, int n_in,
                              void* d_out, int out_size, void* d_ws, size_t ws_size,
                              hipStream_t stream) {
    const float* Qh = (const float*)d_in[0];
    const float* Dh = (const float*)d_in[1];
    const float* W  = (const float*)d_in[2];
    const unsigned char* dm = (const unsigned char*)d_in[3];
    float* out = (float*)d_out;
    char* ws = (char*)d_ws;

    short*          Wbf   = (short*)(ws + WS_OFF_W);
    unsigned short* maskT = (unsigned short*)(ws + WS_OFF_MASK);
    short*          Qn    = (short*)(ws + WS_OFF_QN);
    short*          Dn    = (short*)(ws + WS_OFF_DN);

    prep<<<97, 256, 0, stream>>>(W, Wbf, dm, maskT);
    proj_norm<<<NTOK / 16, 256, 0, stream>>>(Qh, Dh, Wbf, Qn, Dn);
    maxsim<<<512, 512, 0, stream>>>(Qn, Dn, maskT, out);
}

// Round 13
// 41.586 us; speedup vs baseline: 1.6343x; 1.6343x over previous
//
#include <hip/hip_runtime.h>
#include <hip/hip_bf16.h>
#include <math.h>

typedef __attribute__((ext_vector_type(4))) float f32x4;
typedef __attribute__((ext_vector_type(8))) short bf16x8;

#define NB    64
#define LQ    32
#define LDOC  256
#define HDIM  768
#define DDIM  128
#define NTOK_Q (NB * LQ)        // 2048
#define NTOK_D (NB * LDOC)      // 16384
#define NTOK   (NTOK_Q + NTOK_D) // 18432

// ws layout (bytes):
#define WS_OFF_W    0           // Wbf   : 128*768 bf16   (196608)
#define WS_OFF_MASK 196608      // maskT : 64*16 ushort (2KB)
#define WS_OFF_QN   212992      // Qn    : 2048*128 bf16
#define WS_OFF_DN   737280      // Dn    : 16384*128 bf16

__device__ inline short f2bf(float f) {
    unsigned u = __float_as_uint(f);
    u = (u + 0x7fffu + ((u >> 16) & 1u)) >> 16;   // RNE
    return (short)u;
}

// ---------------------------------------------------------------------------
// prep: blocks 0..95 convert W fp32->bf16; block 96 builds bit-transposed mask.
__global__ void prep(const float* __restrict__ W, short* __restrict__ Wbf,
                     const unsigned char* __restrict__ mraw,
                     unsigned short* __restrict__ maskT) {
    if (blockIdx.x < 96) {
        int i = blockIdx.x * 256 + threadIdx.x;
        float4 v = *(const float4*)(W + (size_t)i * 4);
        short4 o;
        o.x = f2bf(v.x); o.y = f2bf(v.y); o.z = f2bf(v.z); o.w = f2bf(v.w);
        *(short4*)(Wbf + (size_t)i * 4) = o;
        return;
    }
    __shared__ int dword_ok_s;
    if (threadIdx.x == 0) dword_ok_s = 1;
    __syncthreads();
    const unsigned* dw = (const unsigned*)mraw;
    int ok = 1;
    for (int i = threadIdx.x; i < 4096; i += 256) {   // first 16KB: safe both ways
        unsigned v = dw[i];
        if (!(v == 0u || v == 1u || v == 0x3F800000u)) ok = 0;
    }
    if (!ok) atomicAnd(&dword_ok_s, 0);
    __syncthreads();
    const int isdw = dword_ok_s;
    for (int w = threadIdx.x; w < 1024; w += 256) {   // word w: c=w>>4, lane-col=w&15
        const int c = w >> 4, lcc = w & 15;
        unsigned bits = 0;
        if (isdw) {
            for (int nt = 0; nt < 16; ++nt)
                bits |= (dw[c * 256 + nt * 16 + lcc] ? 1u : 0u) << nt;
        } else {
            for (int nt = 0; nt < 16; ++nt)
                bits |= (mraw[c * 256 + nt * 16 + lcc] ? 1u : 0u) << nt;
        }
        maskT[w] = (unsigned short)bits;
    }
}

// ---------------------------------------------------------------------------
// Projection + L2 norm v10: REG-STAGED 2-phase pipeline (no global_load_lds).
// Block = 32 rows x 128 cols, BK=64, 12 steps, 4 waves (2x2 of 16x64).
// Per step/thread: issue 6 plain 16B global loads for tile t+1 BEFORE
// compute(t) (sched_barrier-pinned), convert + ds_write after compute,
// one barrier per step. LDS 40KB -> 4 blocks/CU.
__global__ __launch_bounds__(256)
void proj_norm(const float* __restrict__ Qh, const float* __restrict__ Dh,
               const short* __restrict__ Wbf,
               short* __restrict__ Qn, short* __restrict__ Dn) {
    const int tid  = threadIdx.x;
    const int lane = tid & 63;
    const int wave = tid >> 6;
    const int g    = lane >> 4;
    const int lc   = lane & 15;
    const int wr   = wave >> 1;          // 16-row half
    const int wc   = wave & 1;           // 64-col half
    const int row0 = blockIdx.x * 32;

    const float* Asrc = (row0 < NTOK_Q) ? Qh + (size_t)row0 * HDIM
                                        : Dh + (size_t)(row0 - NTOK_Q) * HDIM;

    __shared__ alignas(16) short As[2][2048];   // [buf][row*64 + unit*8], 4KB each
    __shared__ alignas(16) short Bs[2][8192];   // [buf][n*64 + unit*8],  16KB each
    __shared__ float norms[2][2][16];

    // --- per-thread staging assignment (static) ---
    const int arow = tid >> 3, au = tid & 7;
    const float* aga  = Asrc + (size_t)arow * HDIM + au * 8;
    const int    adst = arow * 64 + (au ^ (arow & 7)) * 8;
    const int n0 = tid >> 3,           u0 = tid & 7;
    const int n1 = (256 + tid) >> 3;
    const int n2 = (512 + tid) >> 3;
    const int n3 = (768 + tid) >> 3;
    const short* bga0 = Wbf + (size_t)n0 * HDIM + u0 * 8;
    const short* bga1 = Wbf + (size_t)n1 * HDIM + u0 * 8;
    const short* bga2 = Wbf + (size_t)n2 * HDIM + u0 * 8;
    const short* bga3 = Wbf + (size_t)n3 * HDIM + u0 * 8;
    const int bd0 = n0 * 64 + (u0 ^ (n0 & 7)) * 8;
    const int bd1 = n1 * 64 + (u0 ^ (n1 & 7)) * 8;
    const int bd2 = n2 * 64 + (u0 ^ (n2 & 7)) * 8;
    const int bd3 = n3 * 64 + (u0 ^ (n3 & 7)) * 8;

    float4 ar0, ar1;
    bf16x8 br0, br1, br2, br3;

    auto LOADS = [&](int t) {
        ar0 = *(const float4*)(aga + t * 64);
        ar1 = *(const float4*)(aga + t * 64 + 4);
        br0 = *(const bf16x8*)(bga0 + t * 64);
        br1 = *(const bf16x8*)(bga1 + t * 64);
        br2 = *(const bf16x8*)(bga2 + t * 64);
        br3 = *(const bf16x8*)(bga3 + t * 64);
    };
    auto WRITES = [&](int buf) {
        bf16x8 av;
        av[0] = f2bf(ar0.x); av[1] = f2bf(ar0.y); av[2] = f2bf(ar0.z); av[3] = f2bf(ar0.w);
        av[4] = f2bf(ar1.x); av[5] = f2bf(ar1.y); av[6] = f2bf(ar1.z); av[7] = f2bf(ar1.w);
        *(bf16x8*)(&As[buf][adst]) = av;
        *(bf16x8*)(&Bs[buf][bd0]) = br0;
        *(bf16x8*)(&Bs[buf][bd1]) = br1;
        *(bf16x8*)(&Bs[buf][bd2]) = br2;
        *(bf16x8*)(&Bs[buf][bd3]) = br3;
    };

    f32x4 acc[4];
#pragma unroll
    for (int nt = 0; nt < 4; ++nt) acc[nt] = (f32x4){0.f, 0.f, 0.f, 0.f};

    LOADS(0);
    WRITES(0);
    __syncthreads();

    for (int t = 0; t < 12; ++t) {
        const int cur = t & 1;
        if (t < 11) LOADS(t + 1);               // HBM latency hides under compute
        __builtin_amdgcn_sched_barrier(0);      // pin load issue above compute

        const short* Ab = &As[cur][0];
        const short* Bb = &Bs[cur][0];
#pragma unroll
        for (int ks = 0; ks < 2; ++ks) {
            bf16x8 bfr[4];
#pragma unroll
            for (int nt = 0; nt < 4; ++nt) {
                const int nl = wc * 64 + nt * 16 + lc;
                const int c8 = (ks * 4 + g) ^ (nl & 7);    // read-side swizzle
                bfr[nt] = *(const bf16x8*)(Bb + (size_t)nl * 64 + c8 * 8);
            }
            const int rl = wr * 16 + lc;
            const int ua = (ks * 4 + g) ^ (rl & 7);        // read-side swizzle
            bf16x8 af = *(const bf16x8*)(Ab + (size_t)rl * 64 + ua * 8);
#pragma unroll
            for (int nt = 0; nt < 4; ++nt)
                acc[nt] = __builtin_amdgcn_mfma_f32_16x16x32_bf16(af, bfr[nt], acc[nt], 0, 0, 0);
        }
        if (t < 11) WRITES(cur ^ 1);            // waits loads via reg dependency
        __syncthreads();
    }

    // row norms: partial over this wave's 64 cols, combine col-halves via LDS
    float part[4];
#pragma unroll
    for (int i = 0; i < 4; ++i) {
        float s = 0.f;
#pragma unroll
        for (int nt = 0; nt < 4; ++nt) s += acc[nt][i] * acc[nt][i];
        s += __shfl_xor(s, 1);
        s += __shfl_xor(s, 2);
        s += __shfl_xor(s, 4);
        s += __shfl_xor(s, 8);
        part[i] = s;
    }
    if (lc == 0) {
#pragma unroll
        for (int i = 0; i < 4; ++i) norms[wr][wc][g * 4 + i] = part[i];
    }
    __syncthreads();

    short* Obase = (row0 < NTOK_Q) ? Qn + (size_t)row0 * DDIM
                                   : Dn + (size_t)(row0 - NTOK_Q) * DDIM;
#pragma unroll
    for (int i = 0; i < 4; ++i) {
        const int rloc = g * 4 + i;                     // within 16-row tile
        const float tot = norms[wr][0][rloc] + norms[wr][1][rloc];
        const float inv = 1.f / fmaxf(sqrtf(tot), 1e-12f);
        short* dst = Obase + (size_t)(wr * 16 + rloc) * DDIM + wc * 64;
#pragma unroll
        for (int nt = 0; nt < 4; ++nt)
            dst[nt * 16 + lc] = f2bf(acc[nt][i] * inv);
    }
}

// ---------------------------------------------------------------------------
// MaxSim v5: reg-staged. Block = (c, 8 b's), 8 waves; wave <-> one b
// (32 q-rows x 256 n). D[c] in 4 chunks of 64 rows, double-buffered;
// per chunk/thread: 2 plain 16B loads issued before compute, 2 swizzled
// ds_writes after. LDS 32KB.
__global__ __launch_bounds__(512)
void maxsim(const short* __restrict__ Qn, const short* __restrict__ Dn,
            const unsigned short* __restrict__ maskT, float* __restrict__ out) {
    const int x  = blockIdx.x & 7;            // XCD (perf heuristic only)
    const int m8 = (blockIdx.x >> 3) & 7;
    const int bg = blockIdx.x >> 6;           // b-group (8 b's)
    const int c  = x * 8 + m8;                // all 8 bg's of a c on one XCD

    const int tid  = threadIdx.x;
    const int wave = tid >> 6;                // 0..7  <-> local b
    const int lane = tid & 63;
    const int g = lane >> 4, lc = lane & 15;

    __shared__ alignas(16) short Ds[2][8192];   // [buf][64 rows * 128], 16KB each

    const short* dsrc = Dn + (size_t)c * LDOC * DDIM;

    const int r0 = tid >> 4,          v0 = tid & 15;
    const int r1 = (512 + tid) >> 4,  v1 = v0;
    const int dd0 = r0 * DDIM + (v0 ^ (r0 & 15)) * 8;
    const int dd1 = r1 * DDIM + (v1 ^ (r1 & 15)) * 8;
    bf16x8 dr0, dr1;

    auto LOADS = [&](int ch) {
        dr0 = *(const bf16x8*)(dsrc + (size_t)(ch * 64 + r0) * DDIM + v0 * 8);
        dr1 = *(const bf16x8*)(dsrc + (size_t)(ch * 64 + r1) * DDIM + v1 * 8);
    };
    auto WRITES = [&](int buf) {
        *(bf16x8*)(&Ds[buf][dd0]) = dr0;
        *(bf16x8*)(&Ds[buf][dd1]) = dr1;
    };

    LOADS(0);
    WRITES(0);

    bf16x8 qf[2][4];
    const int qrow0 = bg * 256 + wave * 32;
#pragma unroll
    for (int m = 0; m < 2; ++m) {
        const short* qb = Qn + (size_t)(qrow0 + m * 16 + lc) * DDIM;
#pragma unroll
        for (int ks = 0; ks < 4; ++ks)
            qf[m][ks] = *(const bf16x8*)(qb + ks * 32 + g * 8);
    }
    const unsigned mbits = maskT[c * 16 + lc];    // bit nt = mask[c][nt*16+lc]

    __syncthreads();   // chunk 0 written

    float rmax[2][4];
#pragma unroll
    for (int m = 0; m < 2; ++m)
#pragma unroll
        for (int i = 0; i < 4; ++i) rmax[m][i] = -INFINITY;

    for (int ch = 0; ch < 4; ++ch) {
        const int buf = ch & 1;
        if (ch < 3) LOADS(ch + 1);                // fly under this chunk's compute
        __builtin_amdgcn_sched_barrier(0);
        const short* Db = &Ds[buf][0];
#pragma unroll
        for (int j = 0; j < 4; ++j) {
            const int rowl = j * 16 + lc;
            bf16x8 bf[4];
#pragma unroll
            for (int ks = 0; ks < 4; ++ks) {
                const int c16 = (ks * 4 + g) ^ lc;     // read-side swizzle
                bf[ks] = *(const bf16x8*)(Db + (size_t)rowl * DDIM + c16 * 8);
            }
            const bool on = (mbits >> (ch * 4 + j)) & 1;
#pragma unroll
            for (int m = 0; m < 2; ++m) {
                f32x4 acc = (f32x4){0.f, 0.f, 0.f, 0.f};
#pragma unroll
                for (int ks = 0; ks < 4; ++ks)
                    acc = __builtin_amdgcn_mfma_f32_16x16x32_bf16(qf[m][ks], bf[ks], acc, 0, 0, 0);
#pragma unroll
                for (int i = 0; i < 4; ++i)
                    rmax[m][i] = on ? fmaxf(rmax[m][i], acc[i]) : rmax[m][i];
            }
        }
        if (ch < 3) WRITES(buf ^ 1);
        __syncthreads();
    }

    float s = 0.f;
#pragma unroll
    for (int m = 0; m < 2; ++m)
#pragma unroll
        for (int i = 0; i < 4; ++i) {
            float r = rmax[m][i];
            r = fmaxf(r, __shfl_xor(r, 1));
            r = fmaxf(r, __shfl_xor(r, 2));
            r = fmaxf(r, __shfl_xor(r, 4));
            r = fmaxf(r, __shfl_xor(r, 8));
            s += r;
        }
    s += __shfl_xor(s, 16);
    s += __shfl_xor(s, 32);

    if (lane == 0) {
        const int b = bg * 8 + wave;
        out[(size_t)b * NB + c] = s;
    }
}

// ---------------------------------------------------------------------------
extern "C" void kernel_launch(void* const* d_in, const int* in_sizes, int n_in,
                              void* d_out, int out_size, void* d_ws, size_t ws_size,
                              hipStream_t stream) {
    const float* Qh = (const float*)d_in[0];
    const float* Dh = (const float*)d_in[1];
    const float* W  = (const float*)d_in[2];
    const unsigned char* dm = (const unsigned char*)d_in[3];
    float* out = (float*)d_out;
    char* ws = (char*)d_ws;

    short*          Wbf   = (short*)(ws + WS_OFF_W);
    unsigned short* maskT = (unsigned short*)(ws + WS_OFF_MASK);
    short*          Qn    = (short*)(ws + WS_OFF_QN);
    short*          Dn    = (short*)(ws + WS_OFF_DN);

    prep<<<97, 256, 0, stream>>>(W, Wbf, dm, maskT);
    proj_norm<<<NTOK / 32, 256, 0, stream>>>(Qh, Dh, Wbf, Qn, Dn);
    maxsim<<<512, 512, 0, stream>>>(Qn, Dn, maskT, out);
}